// Round 9
// baseline (155.128 us; speedup 1.0000x reference)
//
#include <hip/hip_runtime.h>
#include <math.h>

#define K_EMB 512
#define DIM 64
#define NVEC 65536                      // 64*32*32
#define OUT_LOSS 0
#define OUT_Q 1
#define OUT_PERP (1 + NVEC * DIM)       // 4194305
#define OUT_IDX (1 + NVEC * DIM + 1)    // 4194306
#define EPS2 1e-4f                      // ambiguity margin (fast-path err bound ~2e-5)
#define FIX_CAP 16                      // per 64-vec block

typedef __attribute__((ext_vector_type(8))) short short8;   // 8 bf16 (4 VGPRs)
typedef __attribute__((ext_vector_type(4))) float float4v;  // MFMA acc

// ws layout (bytes):
// [0,2048)        csq[512] fp32 (numpy-order)
// [2048,2560)     double sse64[64]
// [2560,4608)     u32 hist[512]
// [4608,70144)    ahi: codebook hi-bf16 A-fragments [t=32][step=2][lane=64][8]
// [70144,135680)  alo: codebook lo-bf16 A-fragments
// [135680,168448) csqf: per-(t,lane) float4 of csq for the fold

__device__ __forceinline__ unsigned short bf16_rn(float f) {
    unsigned u = __float_as_uint(f);
    return (unsigned short)((u + 0x7FFFu + ((u >> 16) & 1u)) >> 16);
}

// numpy pairwise_sum replica for sum(v*v) over 64 elems (products rounded
// before summing, 8 stride-8 chains, pairwise combine) — matches np.sum.
__device__ __forceinline__ float np_pairwise8_sq(const float* v) {
    float r[8];
#pragma unroll
    for (int j = 0; j < 8; ++j) r[j] = __fmul_rn(v[j], v[j]);
#pragma unroll
    for (int i = 8; i < 64; i += 8) {
#pragma unroll
        for (int j = 0; j < 8; ++j) r[j] = __fadd_rn(r[j], __fmul_rn(v[i + j], v[i + j]));
    }
    return __fadd_rn(__fadd_rn(__fadd_rn(r[0], r[1]), __fadd_rn(r[2], r[3])),
                     __fadd_rn(__fadd_rn(r[4], r[5]), __fadd_rn(r[6], r[7])));
}

// One prep kernel (replaces setup + frag + memset): fragments, csq, zeroed
// hist/sse. Kernel boundary -> device-wide visibility for vq_main.
__global__ void vq_frag(const float* __restrict__ codebook, float* __restrict__ csq,
                        unsigned short* __restrict__ ahi, unsigned short* __restrict__ alo,
                        float4* __restrict__ csqf, unsigned* __restrict__ hist,
                        double* __restrict__ sse64) {
    const int id = blockIdx.x * 256 + threadIdx.x;   // 4096 total
    const int t = id >> 7, step = (id >> 6) & 1, lane = id & 63;
    const int m = t * 16 + (lane & 15);              // codebook row (A m-index)
    const int kb = step * 32 + (lane >> 4) * 8;      // A k-index base
    const float* src = codebook + (m << 6) + kb;
    short8 h, l;
#pragma unroll
    for (int j = 0; j < 8; ++j) {
        float f = src[j];
        unsigned short hv = bf16_rn(f);
        float lof = f - __uint_as_float(((unsigned)hv) << 16);
        h[j] = (short)hv;
        l[j] = (short)bf16_rn(lof);
    }
    const int fo = ((t * 2 + step) * 64 + lane) * 8;
    *(short8*)(ahi + fo) = h;
    *(short8*)(alo + fo) = l;
    if (step == 0) {
        const int k0 = t * 16 + (lane >> 4) * 4;     // rows covered by this lane's acc regs
        csqf[t * 64 + lane] = make_float4(np_pairwise8_sq(codebook + (size_t)(k0 + 0) * 64),
                                          np_pairwise8_sq(codebook + (size_t)(k0 + 1) * 64),
                                          np_pairwise8_sq(codebook + (size_t)(k0 + 2) * 64),
                                          np_pairwise8_sq(codebook + (size_t)(k0 + 3) * 64));
    }
    if (id < 512) {
        csq[id] = np_pairwise8_sq(codebook + ((size_t)id << 6));
        hist[id] = 0u;
    }
    if (id >= 512 && id < 576) sse64[id - 512] = 0.0;
}

// Main: block = 64 vecs, 4 waves; wave w owns k-tiles [w*8, w*8+8) for ALL 64
// vecs (vt=4 -> each fragment load feeds 24 MFMA). Cross-wave top-2 tournament
// in LDS. Grid 1024 -> 4 blocks/CU (16 waves/CU).
__launch_bounds__(256, 4)
__global__ void vq_main(const float* __restrict__ inputs, const float* __restrict__ codebook,
                        const float* __restrict__ csq, const unsigned short* __restrict__ ahi,
                        const unsigned short* __restrict__ alo, const float4* __restrict__ csqf,
                        unsigned* __restrict__ hist, double* __restrict__ sse64,
                        float* __restrict__ out) {
    __shared__ __align__(16) float s_x[64 * 68];     // 17.4 KB, stride 68
    __shared__ float s_A[64];
    __shared__ unsigned long long s_t1[4][64];       // per-wave top1/top2
    __shared__ unsigned long long s_t2[4][64];
    __shared__ unsigned long long s_e[64];
    __shared__ int s_fix[FIX_CAP];
    __shared__ int s_nfix;
    __shared__ float s_w[4];

    const int tid = threadIdx.x;
    const int wave = tid >> 6, lane = tid & 63;
    const int vbase = blockIdx.x * 64;

    if (tid == 0) s_nfix = 0;

    // stage x (coalesced b128)
    {
        const float4* src = (const float4*)(inputs + ((size_t)vbase << 6));
#pragma unroll
        for (int i = 0; i < 4; ++i) {
            const int f = i * 256 + tid;
            float4 v = src[f];
            *(float4*)&s_x[(f >> 4) * 68 + (f & 15) * 4] = v;
        }
    }
    __syncthreads();

    // exact numpy-order ||x||^2 per vec
    if (tid < 64) s_A[tid] = np_pairwise8_sq(&s_x[tid * 68]);
    __syncthreads();

    // B-fragments (x) for all 64 vecs: 4 vec-tiles x 2 k-steps, hi+lo
    short8 bhi[4][2], blo[4][2];
#pragma unroll
    for (int vt = 0; vt < 4; ++vt) {
        const int vrow = vt * 16 + (lane & 15);
#pragma unroll
        for (int step = 0; step < 2; ++step) {
            const int kb = step * 32 + (lane >> 4) * 8;
            float4 f0 = *(const float4*)&s_x[vrow * 68 + kb];
            float4 f1 = *(const float4*)&s_x[vrow * 68 + kb + 4];
            const float fs[8] = {f0.x, f0.y, f0.z, f0.w, f1.x, f1.y, f1.z, f1.w};
            short8 h, l;
#pragma unroll
            for (int j = 0; j < 8; ++j) {
                unsigned short hv = bf16_rn(fs[j]);
                float lof = fs[j] - __uint_as_float(((unsigned)hv) << 16);
                h[j] = (short)hv;
                l[j] = (short)bf16_rn(lof);
            }
            bhi[vt][step] = h;
            blo[vt][step] = l;
        }
    }

    unsigned long long e1[4] = {~0ULL, ~0ULL, ~0ULL, ~0ULL};
    unsigned long long e2[4] = {~0ULL, ~0ULL, ~0ULL, ~0ULL};

#pragma unroll 2
    for (int tt = 0; tt < 8; ++tt) {
        const int t = wave * 8 + tt;
        const int fo0 = ((t * 2 + 0) * 64 + lane) * 8;
        const int fo1 = ((t * 2 + 1) * 64 + lane) * 8;
        short8 ah0 = *(const short8*)(ahi + fo0);
        short8 ah1 = *(const short8*)(ahi + fo1);
        short8 al0 = *(const short8*)(alo + fo0);
        short8 al1 = *(const short8*)(alo + fo1);
        float4 cs = csqf[t * 64 + lane];
        const float csr[4] = {cs.x, cs.y, cs.z, cs.w};
#pragma unroll
        for (int vt = 0; vt < 4; ++vt) {
            float4v acc = {0.f, 0.f, 0.f, 0.f};
            acc = __builtin_amdgcn_mfma_f32_16x16x32_bf16(ah0, bhi[vt][0], acc, 0, 0, 0);
            acc = __builtin_amdgcn_mfma_f32_16x16x32_bf16(ah1, bhi[vt][1], acc, 0, 0, 0);
            acc = __builtin_amdgcn_mfma_f32_16x16x32_bf16(ah0, blo[vt][0], acc, 0, 0, 0);
            acc = __builtin_amdgcn_mfma_f32_16x16x32_bf16(ah1, blo[vt][1], acc, 0, 0, 0);
            acc = __builtin_amdgcn_mfma_f32_16x16x32_bf16(al0, bhi[vt][0], acc, 0, 0, 0);
            acc = __builtin_amdgcn_mfma_f32_16x16x32_bf16(al1, bhi[vt][1], acc, 0, 0, 0);
            const float Avt = s_A[vt * 16 + (lane & 15)];
#pragma unroll
            for (int r = 0; r < 4; ++r) {
                // D: col=lane&15 (=vec in tile), row=(lane>>4)*4+r (=codeword in tile)
                float d2 = __fadd_rn(__fsub_rn(Avt, __fmul_rn(2.0f, acc[r])), csr[r]);
                const unsigned k = (unsigned)(t * 16 + (lane >> 4) * 4 + r);
                unsigned long long e = ((unsigned long long)__float_as_uint(d2) << 32) | k;
                if (e < e1[vt]) { e2[vt] = e1[vt]; e1[vt] = e; }
                else if (e < e2[vt]) e2[vt] = e;
            }
        }
    }

    // merge 4 lane-groups (different k-subsets, same vec) then stash per wave
#pragma unroll
    for (int vt = 0; vt < 4; ++vt) {
#pragma unroll
        for (int off = 16; off <= 32; off <<= 1) {
            unsigned long long o1 = __shfl_xor(e1[vt], off);
            unsigned long long o2 = __shfl_xor(e2[vt], off);
            if (o1 < e1[vt]) { e2[vt] = (e1[vt] < o2) ? e1[vt] : o2; e1[vt] = o1; }
            else if (o1 < e2[vt]) e2[vt] = o1;
        }
        if (lane < 16) {
            s_t1[wave][vt * 16 + lane] = e1[vt];
            s_t2[wave][vt * 16 + lane] = e2[vt];
        }
    }
    __syncthreads();

    // cross-wave tournament -> global top-2 per vec
    if (tid < 64) {
        unsigned long long E1 = ~0ULL, E2 = ~0ULL;
#pragma unroll
        for (int w = 0; w < 4; ++w) {
            unsigned long long a = s_t1[w][tid], b = s_t2[w][tid];
            if (a < E1) { E2 = (E1 < b) ? E1 : b; E1 = a; }
            else if (a < E2) E2 = a;
        }
        s_e[tid] = E1;
        float b1 = __uint_as_float((unsigned)(E1 >> 32));
        float b2 = __uint_as_float((unsigned)(E2 >> 32));
        if (__fsub_rn(b2, b1) <= EPS2) {     // ambiguous -> exact replay
            int pos = atomicAdd(&s_nfix, 1);
            if (pos < FIX_CAP) s_fix[pos] = tid;
        }
    }
    __syncthreads();

    // exact numpy-order replay for ambiguous vecs (one wave each)
    {
        int nf = s_nfix; if (nf > FIX_CAP) nf = FIX_CAP;
        for (int f = wave; f < nf; f += 4) {
            const int vloc = s_fix[f];
            const float* xr = &s_x[vloc * 68];   // wave-uniform -> LDS broadcast
            const float A = s_A[vloc];
            unsigned long long best = ~0ULL;
#pragma unroll 1
            for (int r8 = 0; r8 < 8; ++r8) {
                const int k = lane * 8 + r8;
                const float* c = codebook + (k << 6);
                float p[8] = {0.f, 0.f, 0.f, 0.f, 0.f, 0.f, 0.f, 0.f};
#pragma unroll
                for (int ii = 0; ii < 64; ii += 8)
#pragma unroll
                    for (int j = 0; j < 8; ++j)
                        p[j] = __builtin_fmaf(xr[ii + j], c[ii + j], p[j]);
                float dot = __fadd_rn(__fadd_rn(__fadd_rn(p[0], p[1]), __fadd_rn(p[2], p[3])),
                                      __fadd_rn(__fadd_rn(p[4], p[5]), __fadd_rn(p[6], p[7])));
                float d2 = __fadd_rn(__fsub_rn(A, __fmul_rn(2.0f, dot)), csq[k]);
                unsigned long long e = ((unsigned long long)__float_as_uint(d2) << 32) | (unsigned)k;
                if (e < best) best = e;
            }
#pragma unroll
            for (int off = 32; off > 0; off >>= 1) {
                unsigned long long o = __shfl_down(best, off);
                if (o < best) best = o;
            }
            if (lane == 0) s_e[vloc] = best;     // equal-d2 ties -> smallest k
        }
    }
    __syncthreads();

    // epilogue: indices + direct hist atomics (64/block, spread addresses)
    if (tid < 64) {
        const unsigned kf = (unsigned)s_e[tid];
        out[OUT_IDX + vbase + tid] = (float)kf;
        atomicAdd(&hist[kf], 1u);
    }
    // quantized (coalesced b128) + sse
    {
        float4* dst = (float4*)(out + OUT_Q + ((size_t)vbase << 6));
        float es = 0.f;
#pragma unroll
        for (int i = 0; i < 4; ++i) {
            const int f = i * 256 + tid;
            const int row = f >> 4, col = (f & 15) * 4;
            const unsigned k = (unsigned)s_e[row];
            float4 qv = *(const float4*)(codebook + ((size_t)k << 6) + col);
            dst[f] = qv;
            float4 xv = *(const float4*)&s_x[row * 68 + col];
            float d0 = qv.x - xv.x; es = __builtin_fmaf(d0, d0, es);
            float d1 = qv.y - xv.y; es = __builtin_fmaf(d1, d1, es);
            float d2 = qv.z - xv.z; es = __builtin_fmaf(d2, d2, es);
            float d3 = qv.w - xv.w; es = __builtin_fmaf(d3, d3, es);
        }
#pragma unroll
        for (int off = 32; off > 0; off >>= 1) es += __shfl_down(es, off);
        if (lane == 0) s_w[wave] = es;
    }
    __syncthreads();
    if (tid == 0)
        atomicAdd(&sse64[blockIdx.x & 63],
                  (double)(((s_w[0] + s_w[1]) + (s_w[2] + s_w[3]))));
}

// final stats: kernel boundary gives device-wide visibility of hist/sse
__global__ void vq_final(const unsigned* __restrict__ hist, const double* __restrict__ sse64,
                         float* __restrict__ out) {
    __shared__ float s_wsm[8];
    const int k = threadIdx.x;  // 512 threads
    float pr = (float)hist[k] / 65536.0f;
    float v = __fmul_rn(pr, logf(__fadd_rn(pr, 1e-10f)));
#pragma unroll
    for (int off = 32; off > 0; off >>= 1) v += __shfl_down(v, off);
    if ((k & 63) == 0) s_wsm[k >> 6] = v;
    __syncthreads();
    if (k == 0) {
        float S = 0.f;
#pragma unroll
        for (int i = 0; i < 8; ++i) S += s_wsm[i];
        out[OUT_PERP] = expf(-S);
        double sv = 0.0;
        for (int i = 0; i < 64; ++i) sv += sse64[i];
        float m = (float)(sv / 4194304.0);            // exact /2^22
        out[OUT_LOSS] = __fadd_rn(m, __fmul_rn(0.25f, m));
    }
}

extern "C" void kernel_launch(void* const* d_in, const int* in_sizes, int n_in,
                              void* d_out, int out_size, void* d_ws, size_t ws_size,
                              hipStream_t stream) {
    const float* inputs   = (const float*)d_in[0];
    const float* codebook = (const float*)d_in[1];
    float* out = (float*)d_out;
    float*          csq   = (float*)d_ws;
    double*         sse64 = (double*)((char*)d_ws + 2048);
    unsigned*       hist  = (unsigned*)((char*)d_ws + 2560);
    unsigned short* ahi   = (unsigned short*)((char*)d_ws + 4608);
    unsigned short* alo   = (unsigned short*)((char*)d_ws + 70144);
    float4*         csqf  = (float4*)((char*)d_ws + 135680);

    vq_frag<<<16, 256, 0, stream>>>(codebook, csq, ahi, alo, csqf, hist, sse64);
    vq_main<<<1024, 256, 0, stream>>>(inputs, codebook, csq, ahi, alo, csqf, hist, sse64, out);
    vq_final<<<1, 512, 0, stream>>>(hist, sse64, out);
}

// Round 10
// 137.151 us; speedup vs baseline: 1.1311x; 1.1311x over previous
//
#include <hip/hip_runtime.h>
#include <math.h>

#define K_EMB 512
#define DIM 64
#define NVEC 65536                      // 64*32*32
#define OUT_LOSS 0
#define OUT_Q 1
#define OUT_PERP (1 + NVEC * DIM)       // 4194305
#define OUT_IDX (1 + NVEC * DIM + 1)    // 4194306
#define EPS2 1e-4f                      // ambiguity margin (fast-path err bound ~2e-5)
#define FIX_CAP 16                      // per 32-vec block

typedef __attribute__((ext_vector_type(8))) short short8;   // 8 bf16 (4 VGPRs)
typedef __attribute__((ext_vector_type(4))) float float4v;  // MFMA acc

// ws layout (bytes):
// [0,2048)        csq[512] fp32 (numpy-order)
// [2048,2560)     double sse64[64]
// [2560,4608)     u32 hist[512]
// [4608,70144)    ahi: codebook hi-bf16 A-fragments [t=32][step=2][lane=64][8]
// [70144,135680)  alo: codebook lo-bf16 A-fragments
// [135680,168448) csqf: per-(t,lane) float4 of csq for the fold

__device__ __forceinline__ unsigned short bf16_rn(float f) {
    unsigned u = __float_as_uint(f);
    return (unsigned short)((u + 0x7FFFu + ((u >> 16) & 1u)) >> 16);
}

// numpy pairwise_sum replica for sum(v*v) over 64 elems (products rounded
// before summing, 8 stride-8 chains, pairwise combine) — matches np.sum.
__device__ __forceinline__ float np_pairwise8_sq(const float* v) {
    float r[8];
#pragma unroll
    for (int j = 0; j < 8; ++j) r[j] = __fmul_rn(v[j], v[j]);
#pragma unroll
    for (int i = 8; i < 64; i += 8) {
#pragma unroll
        for (int j = 0; j < 8; ++j) r[j] = __fadd_rn(r[j], __fmul_rn(v[i + j], v[i + j]));
    }
    return __fadd_rn(__fadd_rn(__fadd_rn(r[0], r[1]), __fadd_rn(r[2], r[3])),
                     __fadd_rn(__fadd_rn(r[4], r[5]), __fadd_rn(r[6], r[7])));
}

// Prep: blocks 0..15 build A-fragments; block 16 computes csq once (into LDS),
// derives csqf from it, zeroes hist/sse. Kernel boundary -> visible to vq_main.
__global__ void vq_frag(const float* __restrict__ codebook, float* __restrict__ csq,
                        unsigned short* __restrict__ ahi, unsigned short* __restrict__ alo,
                        float4* __restrict__ csqf, unsigned* __restrict__ hist,
                        double* __restrict__ sse64) {
    const int tid = threadIdx.x;
    if (blockIdx.x < 16) {
        const int id = blockIdx.x * 256 + tid;           // 4096 conversions
        const int t = id >> 7, step = (id >> 6) & 1, lane = id & 63;
        const int m = t * 16 + (lane & 15);              // codebook row (A m-index)
        const int kb = step * 32 + (lane >> 4) * 8;      // A k-index base
        const float4* src = (const float4*)(codebook + (m << 6) + kb);
        float4 f0 = src[0], f1 = src[1];
        const float fs[8] = {f0.x, f0.y, f0.z, f0.w, f1.x, f1.y, f1.z, f1.w};
        short8 h, l;
#pragma unroll
        for (int j = 0; j < 8; ++j) {
            unsigned short hv = bf16_rn(fs[j]);
            float lof = fs[j] - __uint_as_float(((unsigned)hv) << 16);
            h[j] = (short)hv;
            l[j] = (short)bf16_rn(lof);
        }
        const int fo = ((t * 2 + step) * 64 + lane) * 8;
        *(short8*)(ahi + fo) = h;
        *(short8*)(alo + fo) = l;
    } else {
        __shared__ float s_csq[512];
#pragma unroll
        for (int r = 0; r < 2; ++r) {
            const int k = tid + 256 * r;
            float v = np_pairwise8_sq(codebook + ((size_t)k << 6));
            s_csq[k] = v;
            csq[k] = v;
            hist[k] = 0u;
        }
        if (tid < 64) sse64[tid] = 0.0;
        __syncthreads();
#pragma unroll
        for (int i = 0; i < 8; ++i) {
            const int id = i * 256 + tid;                // 2048 csqf entries
            const int t = id >> 6, lane = id & 63;
            const int k0 = t * 16 + (lane >> 4) * 4;
            csqf[id] = make_float4(s_csq[k0], s_csq[k0 + 1], s_csq[k0 + 2], s_csq[k0 + 3]);
        }
    }
}

// Main: 32 vecs/block (2 vec-tiles), 4 waves; wave w owns k-tiles [8w,8w+8)
// for BOTH vec-tiles. vt=2 -> 8 persistent B-frag short8 = 32 VGPRs (round-8
// proven no-spill). Grid 2048 -> 8 blocks/CU, 32 waves/CU at 64 VGPR.
__launch_bounds__(256, 4)
__global__ void vq_main(const float* __restrict__ inputs, const float* __restrict__ codebook,
                        const float* __restrict__ csq, const unsigned short* __restrict__ ahi,
                        const unsigned short* __restrict__ alo, const float4* __restrict__ csqf,
                        unsigned* __restrict__ hist, double* __restrict__ sse64,
                        float* __restrict__ out) {
    __shared__ __align__(16) float s_x[32 * 68];     // 8.7 KB, stride 68
    __shared__ float s_A[32];
    __shared__ unsigned long long s_t1[4][32];       // per-wave top1/top2
    __shared__ unsigned long long s_t2[4][32];
    __shared__ unsigned long long s_e[32];
    __shared__ int s_fix[FIX_CAP];
    __shared__ int s_nfix;
    __shared__ float s_w[4];

    const int tid = threadIdx.x;
    const int wave = tid >> 6, lane = tid & 63;
    const int vbase = blockIdx.x * 32;

    if (tid == 0) s_nfix = 0;

    // stage x (coalesced b128): 512 float4, 2 per thread
    {
        const float4* src = (const float4*)(inputs + ((size_t)vbase << 6));
#pragma unroll
        for (int i = 0; i < 2; ++i) {
            const int f = i * 256 + tid;
            float4 v = src[f];
            *(float4*)&s_x[(f >> 4) * 68 + (f & 15) * 4] = v;
        }
    }
    __syncthreads();

    // exact numpy-order ||x||^2 per vec
    if (tid < 32) s_A[tid] = np_pairwise8_sq(&s_x[tid * 68]);
    __syncthreads();

    // B-fragments (x) for all 32 vecs: 2 vec-tiles x 2 k-steps, hi+lo = 32 VGPRs
    short8 bhi[2][2], blo[2][2];
#pragma unroll
    for (int vt = 0; vt < 2; ++vt) {
        const int vrow = vt * 16 + (lane & 15);
#pragma unroll
        for (int step = 0; step < 2; ++step) {
            const int kb = step * 32 + (lane >> 4) * 8;
            float4 f0 = *(const float4*)&s_x[vrow * 68 + kb];
            float4 f1 = *(const float4*)&s_x[vrow * 68 + kb + 4];
            const float fs[8] = {f0.x, f0.y, f0.z, f0.w, f1.x, f1.y, f1.z, f1.w};
            short8 h, l;
#pragma unroll
            for (int j = 0; j < 8; ++j) {
                unsigned short hv = bf16_rn(fs[j]);
                float lof = fs[j] - __uint_as_float(((unsigned)hv) << 16);
                h[j] = (short)hv;
                l[j] = (short)bf16_rn(lof);
            }
            bhi[vt][step] = h;
            blo[vt][step] = l;
        }
    }

    unsigned long long e1[2] = {~0ULL, ~0ULL}, e2[2] = {~0ULL, ~0ULL};

#pragma unroll 2
    for (int tt = 0; tt < 8; ++tt) {
        const int t = wave * 8 + tt;                 // this wave's k-tiles
        const int fo0 = ((t * 2 + 0) * 64 + lane) * 8;
        const int fo1 = ((t * 2 + 1) * 64 + lane) * 8;
        short8 ah0 = *(const short8*)(ahi + fo0);
        short8 ah1 = *(const short8*)(ahi + fo1);
        short8 al0 = *(const short8*)(alo + fo0);
        short8 al1 = *(const short8*)(alo + fo1);
        float4 cs = csqf[t * 64 + lane];
        const float csr[4] = {cs.x, cs.y, cs.z, cs.w};
#pragma unroll
        for (int vt = 0; vt < 2; ++vt) {
            float4v acc = {0.f, 0.f, 0.f, 0.f};
            acc = __builtin_amdgcn_mfma_f32_16x16x32_bf16(ah0, bhi[vt][0], acc, 0, 0, 0);
            acc = __builtin_amdgcn_mfma_f32_16x16x32_bf16(ah1, bhi[vt][1], acc, 0, 0, 0);
            acc = __builtin_amdgcn_mfma_f32_16x16x32_bf16(ah0, blo[vt][0], acc, 0, 0, 0);
            acc = __builtin_amdgcn_mfma_f32_16x16x32_bf16(ah1, blo[vt][1], acc, 0, 0, 0);
            acc = __builtin_amdgcn_mfma_f32_16x16x32_bf16(al0, bhi[vt][0], acc, 0, 0, 0);
            acc = __builtin_amdgcn_mfma_f32_16x16x32_bf16(al1, bhi[vt][1], acc, 0, 0, 0);
            const float Avt = s_A[vt * 16 + (lane & 15)];
#pragma unroll
            for (int r = 0; r < 4; ++r) {
                // D: col=lane&15 (=vec in tile), row=(lane>>4)*4+r (=codeword in tile)
                float d2 = __fadd_rn(__fsub_rn(Avt, __fmul_rn(2.0f, acc[r])), csr[r]);
                const unsigned k = (unsigned)(t * 16 + (lane >> 4) * 4 + r);
                unsigned long long e = ((unsigned long long)__float_as_uint(d2) << 32) | k;
                if (e < e1[vt]) { e2[vt] = e1[vt]; e1[vt] = e; }
                else if (e < e2[vt]) e2[vt] = e;
            }
        }
    }

    // merge 4 lane-groups (different k-subsets, same vec) then stash per wave
#pragma unroll
    for (int vt = 0; vt < 2; ++vt) {
#pragma unroll
        for (int off = 16; off <= 32; off <<= 1) {
            unsigned long long o1 = __shfl_xor(e1[vt], off);
            unsigned long long o2 = __shfl_xor(e2[vt], off);
            if (o1 < e1[vt]) { e2[vt] = (e1[vt] < o2) ? e1[vt] : o2; e1[vt] = o1; }
            else if (o1 < e2[vt]) e2[vt] = o1;
        }
        if (lane < 16) {
            s_t1[wave][vt * 16 + lane] = e1[vt];
            s_t2[wave][vt * 16 + lane] = e2[vt];
        }
    }
    __syncthreads();

    // cross-wave tournament -> global top-2 per vec (disjoint ordered k-ranges:
    // u64 compare preserves first-occurrence argmin)
    if (tid < 32) {
        unsigned long long E1 = ~0ULL, E2 = ~0ULL;
#pragma unroll
        for (int w = 0; w < 4; ++w) {
            unsigned long long a = s_t1[w][tid], b = s_t2[w][tid];
            if (a < E1) { E2 = (E1 < b) ? E1 : b; E1 = a; }
            else if (a < E2) E2 = a;
        }
        s_e[tid] = E1;
        float b1 = __uint_as_float((unsigned)(E1 >> 32));
        float b2 = __uint_as_float((unsigned)(E2 >> 32));
        if (__fsub_rn(b2, b1) <= EPS2) {     // ambiguous -> exact replay
            int pos = atomicAdd(&s_nfix, 1);
            if (pos < FIX_CAP) s_fix[pos] = tid;
        }
    }
    __syncthreads();

    // exact numpy-order replay for ambiguous vecs (one wave each; rare)
    {
        int nf = s_nfix; if (nf > FIX_CAP) nf = FIX_CAP;
        for (int f = wave; f < nf; f += 4) {
            const int vloc = s_fix[f];
            const float* xr = &s_x[vloc * 68];   // wave-uniform -> LDS broadcast
            const float A = s_A[vloc];
            unsigned long long best = ~0ULL;
#pragma unroll 1
            for (int r8 = 0; r8 < 8; ++r8) {
                const int k = lane * 8 + r8;
                const float* c = codebook + (k << 6);
                float p[8] = {0.f, 0.f, 0.f, 0.f, 0.f, 0.f, 0.f, 0.f};
#pragma unroll
                for (int ii = 0; ii < 64; ii += 8)
#pragma unroll
                    for (int j = 0; j < 8; ++j)
                        p[j] = __builtin_fmaf(xr[ii + j], c[ii + j], p[j]);
                float dot = __fadd_rn(__fadd_rn(__fadd_rn(p[0], p[1]), __fadd_rn(p[2], p[3])),
                                      __fadd_rn(__fadd_rn(p[4], p[5]), __fadd_rn(p[6], p[7])));
                float d2 = __fadd_rn(__fsub_rn(A, __fmul_rn(2.0f, dot)), csq[k]);
                unsigned long long e = ((unsigned long long)__float_as_uint(d2) << 32) | (unsigned)k;
                if (e < best) best = e;
            }
#pragma unroll
            for (int off = 32; off > 0; off >>= 1) {
                unsigned long long o = __shfl_down(best, off);
                if (o < best) best = o;
            }
            if (lane == 0) s_e[vloc] = best;     // equal-d2 ties -> smallest k
        }
    }
    __syncthreads();

    // epilogue: indices + hist atomics (32/block, spread addresses)
    if (tid < 32) {
        const unsigned kf = (unsigned)s_e[tid];
        out[OUT_IDX + vbase + tid] = (float)kf;
        atomicAdd(&hist[kf], 1u);
    }
    // quantized (coalesced b128) + sse
    {
        float4* dst = (float4*)(out + OUT_Q + ((size_t)vbase << 6));
        float es = 0.f;
#pragma unroll
        for (int i = 0; i < 2; ++i) {
            const int f = i * 256 + tid;
            const int row = f >> 4, col = (f & 15) * 4;
            const unsigned k = (unsigned)s_e[row];
            float4 qv = *(const float4*)(codebook + ((size_t)k << 6) + col);
            dst[f] = qv;
            float4 xv = *(const float4*)&s_x[row * 68 + col];
            float d0 = qv.x - xv.x; es = __builtin_fmaf(d0, d0, es);
            float d1 = qv.y - xv.y; es = __builtin_fmaf(d1, d1, es);
            float d2 = qv.z - xv.z; es = __builtin_fmaf(d2, d2, es);
            float d3 = qv.w - xv.w; es = __builtin_fmaf(d3, d3, es);
        }
#pragma unroll
        for (int off = 32; off > 0; off >>= 1) es += __shfl_down(es, off);
        if (lane == 0) s_w[wave] = es;
    }
    __syncthreads();
    if (tid == 0)
        atomicAdd(&sse64[blockIdx.x & 63],
                  (double)(((s_w[0] + s_w[1]) + (s_w[2] + s_w[3]))));
}

// final stats: kernel boundary gives device-wide visibility of hist/sse
__global__ void vq_final(const unsigned* __restrict__ hist, const double* __restrict__ sse64,
                         float* __restrict__ out) {
    __shared__ float s_wsm[8];
    const int k = threadIdx.x;  // 512 threads
    float pr = (float)hist[k] / 65536.0f;
    float v = __fmul_rn(pr, logf(__fadd_rn(pr, 1e-10f)));
#pragma unroll
    for (int off = 32; off > 0; off >>= 1) v += __shfl_down(v, off);
    if ((k & 63) == 0) s_wsm[k >> 6] = v;
    __syncthreads();
    if (k == 0) {
        float S = 0.f;
#pragma unroll
        for (int i = 0; i < 8; ++i) S += s_wsm[i];
        out[OUT_PERP] = expf(-S);
        double sv = 0.0;
        for (int i = 0; i < 64; ++i) sv += sse64[i];
        float m = (float)(sv / 4194304.0);            // exact /2^22
        out[OUT_LOSS] = __fadd_rn(m, __fmul_rn(0.25f, m));
    }
}

extern "C" void kernel_launch(void* const* d_in, const int* in_sizes, int n_in,
                              void* d_out, int out_size, void* d_ws, size_t ws_size,
                              hipStream_t stream) {
    const float* inputs   = (const float*)d_in[0];
    const float* codebook = (const float*)d_in[1];
    float* out = (float*)d_out;
    float*          csq   = (float*)d_ws;
    double*         sse64 = (double*)((char*)d_ws + 2048);
    unsigned*       hist  = (unsigned*)((char*)d_ws + 2560);
    unsigned short* ahi   = (unsigned short*)((char*)d_ws + 4608);
    unsigned short* alo   = (unsigned short*)((char*)d_ws + 70144);
    float4*         csqf  = (float4*)((char*)d_ws + 135680);

    vq_frag<<<17, 256, 0, stream>>>(codebook, csq, ahi, alo, csqf, hist, sse64);
    vq_main<<<2048, 256, 0, stream>>>(inputs, codebook, csq, ahi, alo, csqf, hist, sse64, out);
    vq_final<<<1, 512, 0, stream>>>(hist, sse64, out);
}